// Round 4
// baseline (13947.263 us; speedup 1.0000x reference)
//
#include <hip/hip_runtime.h>
#include <math.h>

#define DD 64

__device__ __forceinline__ float silu_f(float x) {
    return x / (1.0f + __expf(-x));
}

__device__ __forceinline__ unsigned f32_to_bf16_rne(float x) {
    unsigned u = __float_as_uint(x);
    unsigned r = ((u >> 16) & 1u) + 0x7fffu;
    return (u + r) >> 16;
}

// unpack packed bf16x2 (lo = k even, hi = k odd) to two f32
__device__ __forceinline__ float2 bf2_lo_hi(unsigned u) {
    return make_float2(__uint_as_float(u << 16), __uint_as_float(u & 0xffff0000u));
}

// ---------------- Kernel 1a: per-node linear transforms A,B (scalar), C,D (chiral) + out1 init
__global__ __launch_bounds__(256) void node_transform_kernel(
    const float* __restrict__ ns, const float* __restrict__ nc,
    const float* __restrict__ Ws1, const float* __restrict__ Wc1,
    float* __restrict__ A, float* __restrict__ B,
    float* __restrict__ C, float* __restrict__ Dm,
    float* __restrict__ out1, int N)
{
    __shared__ float w1[128 * 64];
    __shared__ float wc1s[128 * 64];
    __shared__ float xs[4][2][64];
    __shared__ float ys[4][2][64];
    int tid = threadIdx.x;
    for (int i = tid; i < 128 * 64 / 4; i += 256) {
        ((float4*)w1)[i]   = ((const float4*)Ws1)[i];
        ((float4*)wc1s)[i] = ((const float4*)Wc1)[i];
    }
    __syncthreads();
    int wave = tid >> 6, lane = tid & 63;
    for (int nb = blockIdx.x * 8; nb < N; nb += gridDim.x * 8) {
        int n0 = nb + wave * 2;
        #pragma unroll
        for (int s = 0; s < 2; ++s) {
            int n = n0 + s;
            float xv = 0.f, yv = 0.f;
            if (n < N) { xv = ns[(size_t)n * DD + lane]; yv = nc[(size_t)n * DD + lane]; }
            xs[wave][s][lane] = xv;
            ys[wave][s][lane] = yv;
        }
        float aA[2] = {0.f, 0.f}, aB[2] = {0.f, 0.f}, aC[2] = {0.f, 0.f}, aD[2] = {0.f, 0.f};
        for (int k = 0; k < 64; ++k) {
            float wa  = w1[k * 64 + lane];
            float wb  = w1[(64 + k) * 64 + lane];
            float wca = wc1s[k * 64 + lane];
            float wcb = wc1s[(64 + k) * 64 + lane];
            #pragma unroll
            for (int s = 0; s < 2; ++s) {
                float xk = xs[wave][s][k];
                float yk = ys[wave][s][k];
                aA[s] += xk * wa;  aB[s] += xk * wb;
                aC[s] += yk * wca; aD[s] += yk * wcb;
            }
        }
        #pragma unroll
        for (int s = 0; s < 2; ++s) {
            int n = n0 + s;
            if (n < N) {
                A[(size_t)n * DD + lane]  = aA[s];
                B[(size_t)n * DD + lane]  = aB[s];
                C[(size_t)n * DD + lane]  = aC[s];
                Dm[(size_t)n * DD + lane] = aD[s];
                out1[(size_t)n * DD + lane] = ys[wave][s][lane];
            }
        }
    }
}

// ---------------- Kernel 1b: Vv = nv@WV + bV, norm, out0 init, out2 init
__global__ __launch_bounds__(256) void node_vector_kernel(
    const float* __restrict__ ns, const float* __restrict__ nv,
    const float* __restrict__ WV, const float* __restrict__ bV,
    float* __restrict__ out0, float* __restrict__ out2, int N)
{
    __shared__ float wv[64 * 64];
    __shared__ float vs[4][2][3][64];
    int tid = threadIdx.x;
    for (int i = tid; i < 64 * 64 / 4; i += 256)
        ((float4*)wv)[i] = ((const float4*)WV)[i];
    __syncthreads();
    int wave = tid >> 6, lane = tid & 63;
    float bVj = bV[lane];
    for (int nb = blockIdx.x * 8; nb < N; nb += gridDim.x * 8) {
        int n0 = nb + wave * 2;
        #pragma unroll
        for (int s = 0; s < 2; ++s) {
            int n = n0 + s;
            float v0 = 0.f, v1 = 0.f, v2 = 0.f;
            if (n < N) {
                v0 = nv[((size_t)n * 3 + 0) * DD + lane];
                v1 = nv[((size_t)n * 3 + 1) * DD + lane];
                v2 = nv[((size_t)n * 3 + 2) * DD + lane];
            }
            vs[wave][s][0][lane] = v0; vs[wave][s][1][lane] = v1; vs[wave][s][2][lane] = v2;
        }
        float a0[2], a1[2], a2[2];
        #pragma unroll
        for (int s = 0; s < 2; ++s) { a0[s] = bVj; a1[s] = bVj; a2[s] = bVj; }
        for (int k = 0; k < 64; ++k) {
            float w = wv[k * 64 + lane];
            #pragma unroll
            for (int s = 0; s < 2; ++s) {
                a0[s] += vs[wave][s][0][k] * w;
                a1[s] += vs[wave][s][1][k] * w;
                a2[s] += vs[wave][s][2][k] * w;
            }
        }
        #pragma unroll
        for (int s = 0; s < 2; ++s) {
            int n = n0 + s;
            if (n < N) {
                float norm = sqrtf(a0[s] * a0[s] + a1[s] * a1[s] + a2[s] * a2[s]);
                float x = ns[(size_t)n * DD + lane];
                out0[(size_t)n * DD + lane] = x * (1.f + norm);
                out2[((size_t)n * 3 + 0) * DD + lane] = vs[wave][s][0][lane];
                out2[((size_t)n * 3 + 1) * DD + lane] = vs[wave][s][1][lane];
                out2[((size_t)n * 3 + 2) * DD + lane] = vs[wave][s][2][lane];
            }
        }
    }
}

// ---------------- Kernel 2: edges — EPW=4, bf16 Ws2 in LDS, 4 waves/SIMD target
#define EPW 4
__global__ __launch_bounds__(256, 4) void edge_kernel(
    const float* __restrict__ A, const float* __restrict__ B,
    const float* __restrict__ nv, const float* __restrict__ pos,
    const int* __restrict__ eidx,
    const float* __restrict__ bs1, const float* __restrict__ Ws2, const float* __restrict__ bs2,
    float* __restrict__ out0, float* __restrict__ out2, int E)
{
    // Ws2 packed: w2p[kp*192 + c] = bf16(Ws2[2kp][c]) | bf16(Ws2[2kp+1][c])<<16
    __shared__ unsigned w2p[32 * 192];          // 24 KiB
    __shared__ float hsh[4][EPW][64];           //  4 KiB
    int tid = threadIdx.x;
    for (int i = tid; i < 32 * 192; i += 256) {
        int kp = i / 192, c = i % 192;
        float a = Ws2[(size_t)(2 * kp) * 192 + c];
        float b = Ws2[(size_t)(2 * kp + 1) * 192 + c];
        w2p[i] = f32_to_bf16_rne(a) | (f32_to_bf16_rne(b) << 16);
    }
    __syncthreads();
    int wave = tid >> 6, lane = tid & 63;
    float b1  = bs1[lane];
    float b2v = bs2[lane], b2e = bs2[64 + lane], b2s = bs2[128 + lane];
    for (long bb = (long)blockIdx.x * (4 * EPW); bb < E; bb += (long)gridDim.x * (4 * EPW)) {
        long e0b = bb + wave * EPW;
        int i0a[EPW], i1a[EPW];
        #pragma unroll
        for (int e = 0; e < EPW; ++e) {
            long eid = e0b + e;
            int i0 = 0, i1 = 0;
            if (eid < E) { int2 p = ((const int2*)eidx)[eid]; i0 = p.x; i1 = p.y; }
            i0a[e] = i0; i1a[e] = i1;
        }
        #pragma unroll
        for (int e = 0; e < EPW; ++e) {
            long eid = e0b + e;
            float h = 0.f;
            if (eid < E)
                h = silu_f(A[(size_t)i0a[e] * DD + lane] + B[(size_t)i1a[e] * DD + lane] + b1);
            hsh[wave][e][lane] = h;
        }
        // matvec h @ Ws2 (bf16 weights, f32 h / f32 accum)
        float agv[EPW], age[EPW], ass[EPW];
        #pragma unroll
        for (int e = 0; e < EPW; ++e) { agv[e] = 0.f; age[e] = 0.f; ass[e] = 0.f; }
        for (int k4 = 0; k4 < 64; k4 += 4) {
            float4 hk[EPW];
            #pragma unroll
            for (int e = 0; e < EPW; ++e) hk[e] = *(const float4*)&hsh[wave][e][k4];
            int kp = k4 >> 1;
            float2 w0a = bf2_lo_hi(w2p[kp * 192 + lane]);
            float2 w0b = bf2_lo_hi(w2p[(kp + 1) * 192 + lane]);
            float2 w1a = bf2_lo_hi(w2p[kp * 192 + 64 + lane]);
            float2 w1b = bf2_lo_hi(w2p[(kp + 1) * 192 + 64 + lane]);
            float2 w2a = bf2_lo_hi(w2p[kp * 192 + 128 + lane]);
            float2 w2b = bf2_lo_hi(w2p[(kp + 1) * 192 + 128 + lane]);
            #pragma unroll
            for (int e = 0; e < EPW; ++e) {
                agv[e] += hk[e].x * w0a.x + hk[e].y * w0a.y + hk[e].z * w0b.x + hk[e].w * w0b.y;
                age[e] += hk[e].x * w1a.x + hk[e].y * w1a.y + hk[e].z * w1b.x + hk[e].w * w1b.y;
                ass[e] += hk[e].x * w2a.x + hk[e].y * w2a.y + hk[e].z * w2b.x + hk[e].w * w2b.y;
            }
        }
        // scatter: batch gathers first, then compute + atomics
        float v0[EPW], v1[EPW], v2[EPW], rx[EPW], ry[EPW], rz[EPW];
        #pragma unroll
        for (int e = 0; e < EPW; ++e) {
            long eid = e0b + e;
            if (eid < E) {
                int i0 = i0a[e], i1 = i1a[e];
                v0[e] = nv[((size_t)i1 * 3 + 0) * DD + lane];
                v1[e] = nv[((size_t)i1 * 3 + 1) * DD + lane];
                v2[e] = nv[((size_t)i1 * 3 + 2) * DD + lane];
                rx[e] = pos[(size_t)i1 * 3 + 0] - pos[(size_t)i0 * 3 + 0];
                ry[e] = pos[(size_t)i1 * 3 + 1] - pos[(size_t)i0 * 3 + 1];
                rz[e] = pos[(size_t)i1 * 3 + 2] - pos[(size_t)i0 * 3 + 2];
            }
        }
        #pragma unroll
        for (int e = 0; e < EPW; ++e) {
            long eid = e0b + e;
            if (eid >= E) break;
            int i0 = i0a[e];
            float gv = agv[e] + b2v, ge = age[e] + b2e;
            unsafeAtomicAdd(&out0[(size_t)i0 * DD + lane], ass[e] + b2s);
            unsafeAtomicAdd(&out2[((size_t)i0 * 3 + 0) * DD + lane], gv * v0[e] + ge * rx[e]);
            unsafeAtomicAdd(&out2[((size_t)i0 * 3 + 1) * DD + lane], gv * v1[e] + ge * ry[e]);
            unsafeAtomicAdd(&out2[((size_t)i0 * 3 + 2) * DD + lane], gv * v2[e] + ge * rz[e]);
        }
    }
}

// ---------------- Kernel 3: triplets — TPW=4, 3 waves/SIMD target
#define TPW 4
__global__ __launch_bounds__(256, 3) void triplet_kernel(
    const float* __restrict__ C, const float* __restrict__ Dm,
    const float* __restrict__ pos, const int* __restrict__ tidx,
    const float* __restrict__ bc1, const float* __restrict__ Wc2, const float* __restrict__ bc2,
    float* __restrict__ out1, int T)
{
    __shared__ float w[64 * 64];
    __shared__ float hsh[4][TPW][64];
    int tid = threadIdx.x;
    for (int i = tid; i < 64 * 64 / 4; i += 256)
        ((float4*)w)[i] = ((const float4*)Wc2)[i];
    __syncthreads();
    int wave = tid >> 6, lane = tid & 63;
    float b1 = bc1[lane];
    float b2 = bc2[lane] * 3.0f;
    for (long bb = (long)blockIdx.x * (4 * TPW); bb < T; bb += (long)gridDim.x * (4 * TPW)) {
        long t0 = bb + wave * TPW;
        int ib[TPW]; float inv[TPW];
        #pragma unroll
        for (int e = 0; e < TPW; ++e) {
            long t = t0 + e;
            float h = 0.f;
            int b = 0;
            float invv = 0.f;
            if (t < T) {
                int4 q = ((const int4*)tidx)[t];
                b = q.x; int t1 = q.y, t2 = q.z, t3 = q.w;
                float hb = C[(size_t)b * DD + lane] + b1;
                float h1 = silu_f(hb + Dm[(size_t)t1 * DD + lane]);
                float h2 = silu_f(hb + Dm[(size_t)t2 * DD + lane]);
                float h3 = silu_f(hb + Dm[(size_t)t3 * DD + lane]);
                h = h1 + h2 + h3;
                double pbx = pos[(size_t)b * 3], pby = pos[(size_t)b * 3 + 1], pbz = pos[(size_t)b * 3 + 2];
                double r1x = pbx - pos[(size_t)t1 * 3], r1y = pby - pos[(size_t)t1 * 3 + 1], r1z = pbz - pos[(size_t)t1 * 3 + 2];
                double r2x = pbx - pos[(size_t)t2 * 3], r2y = pby - pos[(size_t)t2 * 3 + 1], r2z = pbz - pos[(size_t)t2 * 3 + 2];
                double r3x = pbx - pos[(size_t)t3 * 3], r3y = pby - pos[(size_t)t3 * 3 + 1], r3z = pbz - pos[(size_t)t3 * 3 + 2];
                double cx = r2y * r3z - r2z * r3y;
                double cy = r2z * r3x - r2x * r3z;
                double cz = r2x * r3y - r2y * r3x;
                double stp = r1x * cx + r1y * cy + r1z * cz;
                invv = (float)(1.0 / (stp + 0.01));
            }
            ib[e] = b; inv[e] = invv;
            hsh[wave][e][lane] = h;
        }
        float acc[TPW];
        #pragma unroll
        for (int e = 0; e < TPW; ++e) acc[e] = 0.f;
        for (int k4 = 0; k4 < 64; k4 += 4) {
            float4 hk[TPW];
            #pragma unroll
            for (int e = 0; e < TPW; ++e) hk[e] = *(const float4*)&hsh[wave][e][k4];
            #pragma unroll
            for (int kk = 0; kk < 4; ++kk) {
                float wk = w[(k4 + kk) * 64 + lane];
                #pragma unroll
                for (int e = 0; e < TPW; ++e) acc[e] += (&hk[e].x)[kk] * wk;
            }
        }
        #pragma unroll
        for (int e = 0; e < TPW; ++e) {
            long t = t0 + e;
            if (t >= T) break;
            unsafeAtomicAdd(&out1[(size_t)ib[e] * DD + lane], (acc[e] + b2) * inv[e]);
        }
    }
}

extern "C" void kernel_launch(void* const* d_in, const int* in_sizes, int n_in,
                              void* d_out, int out_size, void* d_ws, size_t ws_size,
                              hipStream_t stream)
{
    const float* ns  = (const float*)d_in[0];
    const float* nc  = (const float*)d_in[1];
    const float* nv  = (const float*)d_in[2];
    const float* pos = (const float*)d_in[3];
    const int* eidx  = (const int*)d_in[4];
    const int* tidx  = (const int*)d_in[5];
    const float* Ws1 = (const float*)d_in[6];
    const float* bs1 = (const float*)d_in[7];
    const float* Ws2 = (const float*)d_in[8];
    const float* bs2 = (const float*)d_in[9];
    const float* Wc1 = (const float*)d_in[10];
    const float* bc1 = (const float*)d_in[11];
    const float* Wc2 = (const float*)d_in[12];
    const float* bc2 = (const float*)d_in[13];
    const float* WV  = (const float*)d_in[14];
    const float* bV  = (const float*)d_in[15];

    int N = in_sizes[0] / 64;
    int E = in_sizes[4] / 2;
    int T = in_sizes[5] / 4;

    float* out0 = (float*)d_out;
    float* out1 = out0 + (size_t)N * 64;
    float* out2 = out1 + (size_t)N * 64;

    float* A  = (float*)d_ws;
    float* B  = A + (size_t)N * 64;
    float* C  = B + (size_t)N * 64;
    float* Dm = C + (size_t)N * 64;

    node_transform_kernel<<<2048, 256, 0, stream>>>(ns, nc, Ws1, Wc1, A, B, C, Dm, out1, N);
    node_vector_kernel<<<2048, 256, 0, stream>>>(ns, nv, WV, bV, out0, out2, N);
    edge_kernel<<<4096, 256, 0, stream>>>(A, B, nv, pos, eidx, bs1, Ws2, bs2, out0, out2, E);
    triplet_kernel<<<4096, 256, 0, stream>>>(C, Dm, pos, tidx, bc1, Wc2, bc2, out1, T);
}

// Round 5
// 1463.303 us; speedup vs baseline: 9.5314x; 9.5314x over previous
//
#include <hip/hip_runtime.h>
#include <math.h>

#define DD 64

__device__ __forceinline__ float silu_f(float x) {
    return x / (1.0f + __expf(-x));
}

__device__ __forceinline__ unsigned f32_to_bf16_rne(float x) {
    unsigned u = __float_as_uint(x);
    unsigned r = ((u >> 16) & 1u) + 0x7fffu;
    return (u + r) >> 16;
}

// unpack packed bf16x2 (lo = k even, hi = k odd) to two f32
__device__ __forceinline__ float2 bf2_lo_hi(unsigned u) {
    return make_float2(__uint_as_float(u << 16), __uint_as_float(u & 0xffff0000u));
}

// ---------------- Kernel 1a: per-node linear transforms A,B (scalar), C,D (chiral) + out1 init
__global__ __launch_bounds__(256) void node_transform_kernel(
    const float* __restrict__ ns, const float* __restrict__ nc,
    const float* __restrict__ Ws1, const float* __restrict__ Wc1,
    float* __restrict__ A, float* __restrict__ B,
    float* __restrict__ C, float* __restrict__ Dm,
    float* __restrict__ out1, int N)
{
    __shared__ float w1[128 * 64];
    __shared__ float wc1s[128 * 64];
    __shared__ float xs[4][2][64];
    __shared__ float ys[4][2][64];
    int tid = threadIdx.x;
    for (int i = tid; i < 128 * 64 / 4; i += 256) {
        ((float4*)w1)[i]   = ((const float4*)Ws1)[i];
        ((float4*)wc1s)[i] = ((const float4*)Wc1)[i];
    }
    __syncthreads();
    int wave = tid >> 6, lane = tid & 63;
    for (int nb = blockIdx.x * 8; nb < N; nb += gridDim.x * 8) {
        int n0 = nb + wave * 2;
        #pragma unroll
        for (int s = 0; s < 2; ++s) {
            int n = n0 + s;
            float xv = 0.f, yv = 0.f;
            if (n < N) { xv = ns[(size_t)n * DD + lane]; yv = nc[(size_t)n * DD + lane]; }
            xs[wave][s][lane] = xv;
            ys[wave][s][lane] = yv;
        }
        float aA[2] = {0.f, 0.f}, aB[2] = {0.f, 0.f}, aC[2] = {0.f, 0.f}, aD[2] = {0.f, 0.f};
        for (int k = 0; k < 64; ++k) {
            float wa  = w1[k * 64 + lane];
            float wb  = w1[(64 + k) * 64 + lane];
            float wca = wc1s[k * 64 + lane];
            float wcb = wc1s[(64 + k) * 64 + lane];
            #pragma unroll
            for (int s = 0; s < 2; ++s) {
                float xk = xs[wave][s][k];
                float yk = ys[wave][s][k];
                aA[s] += xk * wa;  aB[s] += xk * wb;
                aC[s] += yk * wca; aD[s] += yk * wcb;
            }
        }
        #pragma unroll
        for (int s = 0; s < 2; ++s) {
            int n = n0 + s;
            if (n < N) {
                A[(size_t)n * DD + lane]  = aA[s];
                B[(size_t)n * DD + lane]  = aB[s];
                C[(size_t)n * DD + lane]  = aC[s];
                Dm[(size_t)n * DD + lane] = aD[s];
                out1[(size_t)n * DD + lane] = ys[wave][s][lane];
            }
        }
    }
}

// ---------------- Kernel 1b: Vv = nv@WV + bV, norm, out0 init, out2 init
__global__ __launch_bounds__(256) void node_vector_kernel(
    const float* __restrict__ ns, const float* __restrict__ nv,
    const float* __restrict__ WV, const float* __restrict__ bV,
    float* __restrict__ out0, float* __restrict__ out2, int N)
{
    __shared__ float wv[64 * 64];
    __shared__ float vs[4][2][3][64];
    int tid = threadIdx.x;
    for (int i = tid; i < 64 * 64 / 4; i += 256)
        ((float4*)wv)[i] = ((const float4*)WV)[i];
    __syncthreads();
    int wave = tid >> 6, lane = tid & 63;
    float bVj = bV[lane];
    for (int nb = blockIdx.x * 8; nb < N; nb += gridDim.x * 8) {
        int n0 = nb + wave * 2;
        #pragma unroll
        for (int s = 0; s < 2; ++s) {
            int n = n0 + s;
            float v0 = 0.f, v1 = 0.f, v2 = 0.f;
            if (n < N) {
                v0 = nv[((size_t)n * 3 + 0) * DD + lane];
                v1 = nv[((size_t)n * 3 + 1) * DD + lane];
                v2 = nv[((size_t)n * 3 + 2) * DD + lane];
            }
            vs[wave][s][0][lane] = v0; vs[wave][s][1][lane] = v1; vs[wave][s][2][lane] = v2;
        }
        float a0[2], a1[2], a2[2];
        #pragma unroll
        for (int s = 0; s < 2; ++s) { a0[s] = bVj; a1[s] = bVj; a2[s] = bVj; }
        for (int k = 0; k < 64; ++k) {
            float w = wv[k * 64 + lane];
            #pragma unroll
            for (int s = 0; s < 2; ++s) {
                a0[s] += vs[wave][s][0][k] * w;
                a1[s] += vs[wave][s][1][k] * w;
                a2[s] += vs[wave][s][2][k] * w;
            }
        }
        #pragma unroll
        for (int s = 0; s < 2; ++s) {
            int n = n0 + s;
            if (n < N) {
                float norm = sqrtf(a0[s] * a0[s] + a1[s] * a1[s] + a2[s] * a2[s]);
                float x = ns[(size_t)n * DD + lane];
                out0[(size_t)n * DD + lane] = x * (1.f + norm);
                out2[((size_t)n * 3 + 0) * DD + lane] = vs[wave][s][0][lane];
                out2[((size_t)n * 3 + 1) * DD + lane] = vs[wave][s][1][lane];
                out2[((size_t)n * 3 + 2) * DD + lane] = vs[wave][s][2][lane];
            }
        }
    }
}

// ---------------- Kernel 2: edges — EPW=4, bf16 Ws2 in LDS, natural register allocation
#define EPW 4
__global__ __launch_bounds__(256) void edge_kernel(
    const float* __restrict__ A, const float* __restrict__ B,
    const float* __restrict__ nv, const float* __restrict__ pos,
    const int* __restrict__ eidx,
    const float* __restrict__ bs1, const float* __restrict__ Ws2, const float* __restrict__ bs2,
    float* __restrict__ out0, float* __restrict__ out2, int E)
{
    // Ws2 packed: w2p[kp*192 + c] = bf16(Ws2[2kp][c]) | bf16(Ws2[2kp+1][c])<<16
    __shared__ unsigned w2p[32 * 192];          // 24 KiB
    __shared__ float hsh[4][EPW][64];           //  4 KiB
    int tid = threadIdx.x;
    for (int i = tid; i < 32 * 192; i += 256) {
        int kp = i / 192, c = i % 192;
        float a = Ws2[(size_t)(2 * kp) * 192 + c];
        float b = Ws2[(size_t)(2 * kp + 1) * 192 + c];
        w2p[i] = f32_to_bf16_rne(a) | (f32_to_bf16_rne(b) << 16);
    }
    __syncthreads();
    int wave = tid >> 6, lane = tid & 63;
    float b1  = bs1[lane];
    float b2v = bs2[lane], b2e = bs2[64 + lane], b2s = bs2[128 + lane];
    for (long bb = (long)blockIdx.x * (4 * EPW); bb < E; bb += (long)gridDim.x * (4 * EPW)) {
        long e0b = bb + wave * EPW;
        int i0a[EPW], i1a[EPW];
        #pragma unroll
        for (int e = 0; e < EPW; ++e) {
            long eid = e0b + e;
            int i0 = 0, i1 = 0;
            if (eid < E) { int2 p = ((const int2*)eidx)[eid]; i0 = p.x; i1 = p.y; }
            i0a[e] = i0; i1a[e] = i1;
        }
        #pragma unroll
        for (int e = 0; e < EPW; ++e) {
            long eid = e0b + e;
            float h = 0.f;
            if (eid < E)
                h = silu_f(A[(size_t)i0a[e] * DD + lane] + B[(size_t)i1a[e] * DD + lane] + b1);
            hsh[wave][e][lane] = h;
        }
        // matvec h @ Ws2 (bf16 weights, f32 h / f32 accum)
        float agv[EPW], age[EPW], ass[EPW];
        #pragma unroll
        for (int e = 0; e < EPW; ++e) { agv[e] = 0.f; age[e] = 0.f; ass[e] = 0.f; }
        for (int k4 = 0; k4 < 64; k4 += 4) {
            float4 hk[EPW];
            #pragma unroll
            for (int e = 0; e < EPW; ++e) hk[e] = *(const float4*)&hsh[wave][e][k4];
            int kp = k4 >> 1;
            float2 w0a = bf2_lo_hi(w2p[kp * 192 + lane]);
            float2 w0b = bf2_lo_hi(w2p[(kp + 1) * 192 + lane]);
            float2 w1a = bf2_lo_hi(w2p[kp * 192 + 64 + lane]);
            float2 w1b = bf2_lo_hi(w2p[(kp + 1) * 192 + 64 + lane]);
            float2 w2a = bf2_lo_hi(w2p[kp * 192 + 128 + lane]);
            float2 w2b = bf2_lo_hi(w2p[(kp + 1) * 192 + 128 + lane]);
            #pragma unroll
            for (int e = 0; e < EPW; ++e) {
                agv[e] += hk[e].x * w0a.x + hk[e].y * w0a.y + hk[e].z * w0b.x + hk[e].w * w0b.y;
                age[e] += hk[e].x * w1a.x + hk[e].y * w1a.y + hk[e].z * w1b.x + hk[e].w * w1b.y;
                ass[e] += hk[e].x * w2a.x + hk[e].y * w2a.y + hk[e].z * w2b.x + hk[e].w * w2b.y;
            }
        }
        // scatter
        #pragma unroll
        for (int e = 0; e < EPW; ++e) {
            long eid = e0b + e;
            if (eid >= E) break;
            int i0 = i0a[e], i1 = i1a[e];
            unsafeAtomicAdd(&out0[(size_t)i0 * DD + lane], ass[e] + b2s);
            float rx = pos[(size_t)i1 * 3 + 0] - pos[(size_t)i0 * 3 + 0];
            float ry = pos[(size_t)i1 * 3 + 1] - pos[(size_t)i0 * 3 + 1];
            float rz = pos[(size_t)i1 * 3 + 2] - pos[(size_t)i0 * 3 + 2];
            float v0 = nv[((size_t)i1 * 3 + 0) * DD + lane];
            float v1 = nv[((size_t)i1 * 3 + 1) * DD + lane];
            float v2 = nv[((size_t)i1 * 3 + 2) * DD + lane];
            float gv = agv[e] + b2v, ge = age[e] + b2e;
            unsafeAtomicAdd(&out2[((size_t)i0 * 3 + 0) * DD + lane], gv * v0 + ge * rx);
            unsafeAtomicAdd(&out2[((size_t)i0 * 3 + 1) * DD + lane], gv * v1 + ge * ry);
            unsafeAtomicAdd(&out2[((size_t)i0 * 3 + 2) * DD + lane], gv * v2 + ge * rz);
        }
    }
}

// ---------------- Kernel 3: triplets — round-3 version (TPW=8, natural allocation)
#define TPW 8
__global__ __launch_bounds__(256) void triplet_kernel(
    const float* __restrict__ C, const float* __restrict__ Dm,
    const float* __restrict__ pos, const int* __restrict__ tidx,
    const float* __restrict__ bc1, const float* __restrict__ Wc2, const float* __restrict__ bc2,
    float* __restrict__ out1, int T)
{
    __shared__ float w[64 * 64];
    __shared__ float hsh[4][TPW][64];
    int tid = threadIdx.x;
    for (int i = tid; i < 64 * 64 / 4; i += 256)
        ((float4*)w)[i] = ((const float4*)Wc2)[i];
    __syncthreads();
    int wave = tid >> 6, lane = tid & 63;
    float b1 = bc1[lane];
    float b2 = bc2[lane] * 3.0f;
    for (long bb = (long)blockIdx.x * (4 * TPW); bb < T; bb += (long)gridDim.x * (4 * TPW)) {
        long t0 = bb + wave * TPW;
        int ib[TPW]; float inv[TPW];
        #pragma unroll
        for (int e = 0; e < TPW; ++e) {
            long t = t0 + e;
            float h = 0.f;
            int b = 0;
            float invv = 0.f;
            if (t < T) {
                int4 q = ((const int4*)tidx)[t];
                b = q.x; int t1 = q.y, t2 = q.z, t3 = q.w;
                float hb = C[(size_t)b * DD + lane] + b1;
                float h1 = silu_f(hb + Dm[(size_t)t1 * DD + lane]);
                float h2 = silu_f(hb + Dm[(size_t)t2 * DD + lane]);
                float h3 = silu_f(hb + Dm[(size_t)t3 * DD + lane]);
                h = h1 + h2 + h3;
                double pbx = pos[(size_t)b * 3], pby = pos[(size_t)b * 3 + 1], pbz = pos[(size_t)b * 3 + 2];
                double r1x = pbx - pos[(size_t)t1 * 3], r1y = pby - pos[(size_t)t1 * 3 + 1], r1z = pbz - pos[(size_t)t1 * 3 + 2];
                double r2x = pbx - pos[(size_t)t2 * 3], r2y = pby - pos[(size_t)t2 * 3 + 1], r2z = pbz - pos[(size_t)t2 * 3 + 2];
                double r3x = pbx - pos[(size_t)t3 * 3], r3y = pby - pos[(size_t)t3 * 3 + 1], r3z = pbz - pos[(size_t)t3 * 3 + 2];
                double cx = r2y * r3z - r2z * r3y;
                double cy = r2z * r3x - r2x * r3z;
                double cz = r2x * r3y - r2y * r3x;
                double stp = r1x * cx + r1y * cy + r1z * cz;
                invv = (float)(1.0 / (stp + 0.01));
            }
            ib[e] = b; inv[e] = invv;
            hsh[wave][e][lane] = h;
        }
        float acc[TPW];
        #pragma unroll
        for (int e = 0; e < TPW; ++e) acc[e] = 0.f;
        for (int k4 = 0; k4 < 64; k4 += 4) {
            float4 hk[TPW];
            #pragma unroll
            for (int e = 0; e < TPW; ++e) hk[e] = *(const float4*)&hsh[wave][e][k4];
            #pragma unroll
            for (int kk = 0; kk < 4; ++kk) {
                float wk = w[(k4 + kk) * 64 + lane];
                #pragma unroll
                for (int e = 0; e < TPW; ++e) acc[e] += (&hk[e].x)[kk] * wk;
            }
        }
        #pragma unroll
        for (int e = 0; e < TPW; ++e) {
            long t = t0 + e;
            if (t >= T) break;
            unsafeAtomicAdd(&out1[(size_t)ib[e] * DD + lane], (acc[e] + b2) * inv[e]);
        }
    }
}

extern "C" void kernel_launch(void* const* d_in, const int* in_sizes, int n_in,
                              void* d_out, int out_size, void* d_ws, size_t ws_size,
                              hipStream_t stream)
{
    const float* ns  = (const float*)d_in[0];
    const float* nc  = (const float*)d_in[1];
    const float* nv  = (const float*)d_in[2];
    const float* pos = (const float*)d_in[3];
    const int* eidx  = (const int*)d_in[4];
    const int* tidx  = (const int*)d_in[5];
    const float* Ws1 = (const float*)d_in[6];
    const float* bs1 = (const float*)d_in[7];
    const float* Ws2 = (const float*)d_in[8];
    const float* bs2 = (const float*)d_in[9];
    const float* Wc1 = (const float*)d_in[10];
    const float* bc1 = (const float*)d_in[11];
    const float* Wc2 = (const float*)d_in[12];
    const float* bc2 = (const float*)d_in[13];
    const float* WV  = (const float*)d_in[14];
    const float* bV  = (const float*)d_in[15];

    int N = in_sizes[0] / 64;
    int E = in_sizes[4] / 2;
    int T = in_sizes[5] / 4;

    float* out0 = (float*)d_out;
    float* out1 = out0 + (size_t)N * 64;
    float* out2 = out1 + (size_t)N * 64;

    float* A  = (float*)d_ws;
    float* B  = A + (size_t)N * 64;
    float* C  = B + (size_t)N * 64;
    float* Dm = C + (size_t)N * 64;

    node_transform_kernel<<<2048, 256, 0, stream>>>(ns, nc, Ws1, Wc1, A, B, C, Dm, out1, N);
    node_vector_kernel<<<2048, 256, 0, stream>>>(ns, nv, WV, bV, out0, out2, N);
    edge_kernel<<<4096, 256, 0, stream>>>(A, B, nv, pos, eidx, bs1, Ws2, bs2, out0, out2, E);
    triplet_kernel<<<2048, 256, 0, stream>>>(C, Dm, pos, tidx, bc1, Wc2, bc2, out1, T);
}

// Round 6
// 1263.686 us; speedup vs baseline: 11.0370x; 1.1580x over previous
//
#include <hip/hip_runtime.h>
#include <math.h>

#define DD 64

__device__ __forceinline__ float silu_f(float x) {
    return x / (1.0f + __expf(-x));
}

__device__ __forceinline__ unsigned f32_to_bf16_rne(float x) {
    unsigned u = __float_as_uint(x);
    unsigned r = ((u >> 16) & 1u) + 0x7fffu;
    return (u + r) >> 16;
}

// unpack packed bf16x2 (lo = k even, hi = k odd) to two f32
__device__ __forceinline__ float2 bf2_lo_hi(unsigned u) {
    return make_float2(__uint_as_float(u << 16), __uint_as_float(u & 0xffff0000u));
}

// async row-gather: per-lane global source, wave-uniform LDS base + lane*4
__device__ __forceinline__ void gload_lds4(const float* gsrc, float* lds_base) {
    __builtin_amdgcn_global_load_lds(
        (const __attribute__((address_space(1))) void*)gsrc,
        (__attribute__((address_space(3))) void*)lds_base,
        4, 0, 0);
}

// ---------------- Kernel 1a: per-node linear transforms A,B (scalar), C,D (chiral) + out1 init
__global__ __launch_bounds__(256) void node_transform_kernel(
    const float* __restrict__ ns, const float* __restrict__ nc,
    const float* __restrict__ Ws1, const float* __restrict__ Wc1,
    float* __restrict__ A, float* __restrict__ B,
    float* __restrict__ C, float* __restrict__ Dm,
    float* __restrict__ out1, int N)
{
    __shared__ float w1[128 * 64];
    __shared__ float wc1s[128 * 64];
    __shared__ float xs[4][2][64];
    __shared__ float ys[4][2][64];
    int tid = threadIdx.x;
    for (int i = tid; i < 128 * 64 / 4; i += 256) {
        ((float4*)w1)[i]   = ((const float4*)Ws1)[i];
        ((float4*)wc1s)[i] = ((const float4*)Wc1)[i];
    }
    __syncthreads();
    int wave = tid >> 6, lane = tid & 63;
    for (int nb = blockIdx.x * 8; nb < N; nb += gridDim.x * 8) {
        int n0 = nb + wave * 2;
        #pragma unroll
        for (int s = 0; s < 2; ++s) {
            int n = n0 + s;
            float xv = 0.f, yv = 0.f;
            if (n < N) { xv = ns[(size_t)n * DD + lane]; yv = nc[(size_t)n * DD + lane]; }
            xs[wave][s][lane] = xv;
            ys[wave][s][lane] = yv;
        }
        float aA[2] = {0.f, 0.f}, aB[2] = {0.f, 0.f}, aC[2] = {0.f, 0.f}, aD[2] = {0.f, 0.f};
        for (int k = 0; k < 64; ++k) {
            float wa  = w1[k * 64 + lane];
            float wb  = w1[(64 + k) * 64 + lane];
            float wca = wc1s[k * 64 + lane];
            float wcb = wc1s[(64 + k) * 64 + lane];
            #pragma unroll
            for (int s = 0; s < 2; ++s) {
                float xk = xs[wave][s][k];
                float yk = ys[wave][s][k];
                aA[s] += xk * wa;  aB[s] += xk * wb;
                aC[s] += yk * wca; aD[s] += yk * wcb;
            }
        }
        #pragma unroll
        for (int s = 0; s < 2; ++s) {
            int n = n0 + s;
            if (n < N) {
                A[(size_t)n * DD + lane]  = aA[s];
                B[(size_t)n * DD + lane]  = aB[s];
                C[(size_t)n * DD + lane]  = aC[s];
                Dm[(size_t)n * DD + lane] = aD[s];
                out1[(size_t)n * DD + lane] = ys[wave][s][lane];
            }
        }
    }
}

// ---------------- Kernel 1b: Vv = nv@WV + bV, norm, out0 init, out2 init
__global__ __launch_bounds__(256) void node_vector_kernel(
    const float* __restrict__ ns, const float* __restrict__ nv,
    const float* __restrict__ WV, const float* __restrict__ bV,
    float* __restrict__ out0, float* __restrict__ out2, int N)
{
    __shared__ float wv[64 * 64];
    __shared__ float vs[4][2][3][64];
    int tid = threadIdx.x;
    for (int i = tid; i < 64 * 64 / 4; i += 256)
        ((float4*)wv)[i] = ((const float4*)WV)[i];
    __syncthreads();
    int wave = tid >> 6, lane = tid & 63;
    float bVj = bV[lane];
    for (int nb = blockIdx.x * 8; nb < N; nb += gridDim.x * 8) {
        int n0 = nb + wave * 2;
        #pragma unroll
        for (int s = 0; s < 2; ++s) {
            int n = n0 + s;
            float v0 = 0.f, v1 = 0.f, v2 = 0.f;
            if (n < N) {
                v0 = nv[((size_t)n * 3 + 0) * DD + lane];
                v1 = nv[((size_t)n * 3 + 1) * DD + lane];
                v2 = nv[((size_t)n * 3 + 2) * DD + lane];
            }
            vs[wave][s][0][lane] = v0; vs[wave][s][1][lane] = v1; vs[wave][s][2][lane] = v2;
        }
        float a0[2], a1[2], a2[2];
        #pragma unroll
        for (int s = 0; s < 2; ++s) { a0[s] = bVj; a1[s] = bVj; a2[s] = bVj; }
        for (int k = 0; k < 64; ++k) {
            float w = wv[k * 64 + lane];
            #pragma unroll
            for (int s = 0; s < 2; ++s) {
                a0[s] += vs[wave][s][0][k] * w;
                a1[s] += vs[wave][s][1][k] * w;
                a2[s] += vs[wave][s][2][k] * w;
            }
        }
        #pragma unroll
        for (int s = 0; s < 2; ++s) {
            int n = n0 + s;
            if (n < N) {
                float norm = sqrtf(a0[s] * a0[s] + a1[s] * a1[s] + a2[s] * a2[s]);
                float x = ns[(size_t)n * DD + lane];
                out0[(size_t)n * DD + lane] = x * (1.f + norm);
                out2[((size_t)n * 3 + 0) * DD + lane] = vs[wave][s][0][lane];
                out2[((size_t)n * 3 + 1) * DD + lane] = vs[wave][s][1][lane];
                out2[((size_t)n * 3 + 2) * DD + lane] = vs[wave][s][2][lane];
            }
        }
    }
}

// ---------------- Kernel 2: edges — async LDS row staging, one drain per group
#define EPW 4
__global__ __launch_bounds__(256) void edge_kernel(
    const float* __restrict__ A, const float* __restrict__ B,
    const float* __restrict__ nv, const float* __restrict__ pos,
    const int* __restrict__ eidx,
    const float* __restrict__ bs1, const float* __restrict__ Ws2, const float* __restrict__ bs2,
    float* __restrict__ out0, float* __restrict__ out2, int E)
{
    __shared__ unsigned w2p[32 * 192];       // 24 KiB bf16-packed Ws2
    __shared__ float stA[4][EPW][64];        // 4 KiB  (A-row, overwritten with h)
    __shared__ float stB[4][EPW][64];        // 4 KiB
    __shared__ float stV[4][EPW][3][64];     // 12 KiB
    int tid = threadIdx.x;
    for (int i = tid; i < 32 * 192; i += 256) {
        int kp = i / 192, c = i % 192;
        float a = Ws2[(size_t)(2 * kp) * 192 + c];
        float b = Ws2[(size_t)(2 * kp + 1) * 192 + c];
        w2p[i] = f32_to_bf16_rne(a) | (f32_to_bf16_rne(b) << 16);
    }
    __syncthreads();
    int wave = __builtin_amdgcn_readfirstlane(tid >> 6);
    int lane = tid & 63;
    float b1  = bs1[lane];
    float b2v = bs2[lane], b2e = bs2[64 + lane], b2s = bs2[128 + lane];
    for (long bb = (long)blockIdx.x * (4 * EPW); bb < E; bb += (long)gridDim.x * (4 * EPW)) {
        long e0b = bb + wave * EPW;
        int i0a[EPW], i1a[EPW];
        #pragma unroll
        for (int e = 0; e < EPW; ++e) {
            long eid = e0b + e;
            int i0 = 0, i1 = 0;
            if (eid < E) { int2 p = ((const int2*)eidx)[eid]; i0 = p.x; i1 = p.y; }
            i0a[e] = __builtin_amdgcn_readfirstlane(i0);
            i1a[e] = __builtin_amdgcn_readfirstlane(i1);
        }
        // issue ALL 20 row-gathers async into LDS (no VGPR staging, max MLP)
        #pragma unroll
        for (int e = 0; e < EPW; ++e) {
            gload_lds4(A + (size_t)i0a[e] * DD + lane, &stA[wave][e][0]);
            gload_lds4(B + (size_t)i1a[e] * DD + lane, &stB[wave][e][0]);
            gload_lds4(nv + ((size_t)i1a[e] * 3 + 0) * DD + lane, &stV[wave][e][0][0]);
            gload_lds4(nv + ((size_t)i1a[e] * 3 + 1) * DD + lane, &stV[wave][e][1][0]);
            gload_lds4(nv + ((size_t)i1a[e] * 3 + 2) * DD + lane, &stV[wave][e][2][0]);
        }
        asm volatile("s_waitcnt vmcnt(0)" ::: "memory");
        // h phase: in-place over stA
        #pragma unroll
        for (int e = 0; e < EPW; ++e) {
            float h = silu_f(stA[wave][e][lane] + stB[wave][e][lane] + b1);
            stA[wave][e][lane] = h;
        }
        // matvec h @ Ws2 (bf16 weights from LDS, broadcast reads)
        float agv[EPW], age[EPW], ass[EPW];
        #pragma unroll
        for (int e = 0; e < EPW; ++e) { agv[e] = 0.f; age[e] = 0.f; ass[e] = 0.f; }
        for (int k4 = 0; k4 < 64; k4 += 4) {
            float4 hk[EPW];
            #pragma unroll
            for (int e = 0; e < EPW; ++e) hk[e] = *(const float4*)&stA[wave][e][k4];
            int kp = k4 >> 1;
            float2 w0a = bf2_lo_hi(w2p[kp * 192 + lane]);
            float2 w0b = bf2_lo_hi(w2p[(kp + 1) * 192 + lane]);
            float2 w1a = bf2_lo_hi(w2p[kp * 192 + 64 + lane]);
            float2 w1b = bf2_lo_hi(w2p[(kp + 1) * 192 + 64 + lane]);
            float2 w2a = bf2_lo_hi(w2p[kp * 192 + 128 + lane]);
            float2 w2b = bf2_lo_hi(w2p[(kp + 1) * 192 + 128 + lane]);
            #pragma unroll
            for (int e = 0; e < EPW; ++e) {
                agv[e] += hk[e].x * w0a.x + hk[e].y * w0a.y + hk[e].z * w0b.x + hk[e].w * w0b.y;
                age[e] += hk[e].x * w1a.x + hk[e].y * w1a.y + hk[e].z * w1b.x + hk[e].w * w1b.y;
                ass[e] += hk[e].x * w2a.x + hk[e].y * w2a.y + hk[e].z * w2b.x + hk[e].w * w2b.y;
            }
        }
        // scatter: V rows from LDS, pos via scalar loads (indices are SGPR)
        #pragma unroll
        for (int e = 0; e < EPW; ++e) {
            long eid = e0b + e;
            if (eid >= E) break;
            int i0 = i0a[e], i1 = i1a[e];
            unsafeAtomicAdd(&out0[(size_t)i0 * DD + lane], ass[e] + b2s);
            float rx = pos[(size_t)i1 * 3 + 0] - pos[(size_t)i0 * 3 + 0];
            float ry = pos[(size_t)i1 * 3 + 1] - pos[(size_t)i0 * 3 + 1];
            float rz = pos[(size_t)i1 * 3 + 2] - pos[(size_t)i0 * 3 + 2];
            float v0 = stV[wave][e][0][lane];
            float v1 = stV[wave][e][1][lane];
            float v2 = stV[wave][e][2][lane];
            float gv = agv[e] + b2v, ge = age[e] + b2e;
            unsafeAtomicAdd(&out2[((size_t)i0 * 3 + 0) * DD + lane], gv * v0 + ge * rx);
            unsafeAtomicAdd(&out2[((size_t)i0 * 3 + 1) * DD + lane], gv * v1 + ge * ry);
            unsafeAtomicAdd(&out2[((size_t)i0 * 3 + 2) * DD + lane], gv * v2 + ge * rz);
        }
    }
}

// ---------------- Kernel 3: triplets — async LDS row staging, TPW=4
#define TPW 4
__global__ __launch_bounds__(256) void triplet_kernel(
    const float* __restrict__ C, const float* __restrict__ Dm,
    const float* __restrict__ pos, const int* __restrict__ tidx,
    const float* __restrict__ bc1, const float* __restrict__ Wc2, const float* __restrict__ bc2,
    float* __restrict__ out1, int T)
{
    __shared__ float wT[64 * 64];            // 16 KiB
    __shared__ float stC[4][TPW][64];        // 4 KiB (C-row, overwritten with h)
    __shared__ float stD[4][TPW][3][64];     // 12 KiB
    int tid = threadIdx.x;
    for (int i = tid; i < 64 * 64 / 4; i += 256)
        ((float4*)wT)[i] = ((const float4*)Wc2)[i];
    __syncthreads();
    int wave = __builtin_amdgcn_readfirstlane(tid >> 6);
    int lane = tid & 63;
    float b1 = bc1[lane];
    float b2 = bc2[lane] * 3.0f;
    for (long bb = (long)blockIdx.x * (4 * TPW); bb < T; bb += (long)gridDim.x * (4 * TPW)) {
        long t0 = bb + wave * TPW;
        int ib[TPW], it1[TPW], it2[TPW], it3[TPW];
        #pragma unroll
        for (int e = 0; e < TPW; ++e) {
            long t = t0 + e;
            int b = 0, t1 = 0, t2 = 0, t3 = 0;
            if (t < T) { int4 q = ((const int4*)tidx)[t]; b = q.x; t1 = q.y; t2 = q.z; t3 = q.w; }
            ib[e]  = __builtin_amdgcn_readfirstlane(b);
            it1[e] = __builtin_amdgcn_readfirstlane(t1);
            it2[e] = __builtin_amdgcn_readfirstlane(t2);
            it3[e] = __builtin_amdgcn_readfirstlane(t3);
        }
        #pragma unroll
        for (int e = 0; e < TPW; ++e) {
            gload_lds4(C  + (size_t)ib[e]  * DD + lane, &stC[wave][e][0]);
            gload_lds4(Dm + (size_t)it1[e] * DD + lane, &stD[wave][e][0][0]);
            gload_lds4(Dm + (size_t)it2[e] * DD + lane, &stD[wave][e][1][0]);
            gload_lds4(Dm + (size_t)it3[e] * DD + lane, &stD[wave][e][2][0]);
        }
        asm volatile("s_waitcnt vmcnt(0)" ::: "memory");
        float inv[TPW];
        #pragma unroll
        for (int e = 0; e < TPW; ++e) {
            float hb = stC[wave][e][lane] + b1;
            float h = silu_f(hb + stD[wave][e][0][lane])
                    + silu_f(hb + stD[wave][e][1][lane])
                    + silu_f(hb + stD[wave][e][2][lane]);
            stC[wave][e][lane] = h;
            int b = ib[e], t1 = it1[e], t2 = it2[e], t3 = it3[e];
            double pbx = pos[(size_t)b * 3], pby = pos[(size_t)b * 3 + 1], pbz = pos[(size_t)b * 3 + 2];
            double r1x = pbx - pos[(size_t)t1 * 3], r1y = pby - pos[(size_t)t1 * 3 + 1], r1z = pbz - pos[(size_t)t1 * 3 + 2];
            double r2x = pbx - pos[(size_t)t2 * 3], r2y = pby - pos[(size_t)t2 * 3 + 1], r2z = pbz - pos[(size_t)t2 * 3 + 2];
            double r3x = pbx - pos[(size_t)t3 * 3], r3y = pby - pos[(size_t)t3 * 3 + 1], r3z = pbz - pos[(size_t)t3 * 3 + 2];
            double cx = r2y * r3z - r2z * r3y;
            double cy = r2z * r3x - r2x * r3z;
            double cz = r2x * r3y - r2y * r3x;
            double stp = r1x * cx + r1y * cy + r1z * cz;
            inv[e] = (float)(1.0 / (stp + 0.01));
        }
        float acc[TPW];
        #pragma unroll
        for (int e = 0; e < TPW; ++e) acc[e] = 0.f;
        for (int k4 = 0; k4 < 64; k4 += 4) {
            float4 hk[TPW];
            #pragma unroll
            for (int e = 0; e < TPW; ++e) hk[e] = *(const float4*)&stC[wave][e][k4];
            #pragma unroll
            for (int kk = 0; kk < 4; ++kk) {
                float wk = wT[(k4 + kk) * 64 + lane];
                #pragma unroll
                for (int e = 0; e < TPW; ++e) acc[e] += (&hk[e].x)[kk] * wk;
            }
        }
        #pragma unroll
        for (int e = 0; e < TPW; ++e) {
            long t = t0 + e;
            if (t >= T) break;
            unsafeAtomicAdd(&out1[(size_t)ib[e] * DD + lane], (acc[e] + b2) * inv[e]);
        }
    }
}

extern "C" void kernel_launch(void* const* d_in, const int* in_sizes, int n_in,
                              void* d_out, int out_size, void* d_ws, size_t ws_size,
                              hipStream_t stream)
{
    const float* ns  = (const float*)d_in[0];
    const float* nc  = (const float*)d_in[1];
    const float* nv  = (const float*)d_in[2];
    const float* pos = (const float*)d_in[3];
    const int* eidx  = (const int*)d_in[4];
    const int* tidx  = (const int*)d_in[5];
    const float* Ws1 = (const float*)d_in[6];
    const float* bs1 = (const float*)d_in[7];
    const float* Ws2 = (const float*)d_in[8];
    const float* bs2 = (const float*)d_in[9];
    const float* Wc1 = (const float*)d_in[10];
    const float* bc1 = (const float*)d_in[11];
    const float* Wc2 = (const float*)d_in[12];
    const float* bc2 = (const float*)d_in[13];
    const float* WV  = (const float*)d_in[14];
    const float* bV  = (const float*)d_in[15];

    int N = in_sizes[0] / 64;
    int E = in_sizes[4] / 2;
    int T = in_sizes[5] / 4;

    float* out0 = (float*)d_out;
    float* out1 = out0 + (size_t)N * 64;
    float* out2 = out1 + (size_t)N * 64;

    float* A  = (float*)d_ws;
    float* B  = A + (size_t)N * 64;
    float* C  = B + (size_t)N * 64;
    float* Dm = C + (size_t)N * 64;

    node_transform_kernel<<<2048, 256, 0, stream>>>(ns, nc, Ws1, Wc1, A, B, C, Dm, out1, N);
    node_vector_kernel<<<2048, 256, 0, stream>>>(ns, nv, WV, bV, out0, out2, N);
    edge_kernel<<<4096, 256, 0, stream>>>(A, B, nv, pos, eidx, bs1, Ws2, bs2, out0, out2, E);
    triplet_kernel<<<4096, 256, 0, stream>>>(C, Dm, pos, tidx, bc1, Wc2, bc2, out1, T);
}